// Round 3
// baseline (1058.360 us; speedup 1.0000x reference)
//
#include <hip/hip_runtime.h>
#include <hip/hip_bf16.h>

typedef unsigned short u16;
typedef __attribute__((ext_vector_type(8))) short bh8;   // 8 x bf16 (4 VGPRs)
typedef __attribute__((ext_vector_type(4))) float fx4;   // MFMA accumulator

__device__ __forceinline__ u16 f2bf(float f) {
  union { float f; unsigned u; } v; v.f = f;
  unsigned r = v.u + 0x7FFFu + ((v.u >> 16) & 1u);  // RNE
  return (u16)(r >> 16);
}

__device__ __forceinline__ void gload_lds16(const void* g, void* l) {
  __builtin_amdgcn_global_load_lds(
      (const __attribute__((address_space(1))) void*)g,
      (__attribute__((address_space(3))) void*)l, 16, 0, 0);
}

#define VMCNT(n) asm volatile("s_waitcnt vmcnt(" #n ")" ::: "memory")

__device__ __forceinline__ void bar() {
  asm volatile("" ::: "memory");
  __builtin_amdgcn_sched_barrier(0);
  __builtin_amdgcn_s_barrier();
  __builtin_amdgcn_sched_barrier(0);
  asm volatile("" ::: "memory");
}

// ---------------- weight transpose + f32->bf16 : W[K][N] -> Wt[N][K] ----------------
__global__ __launch_bounds__(256) void transp_cvt(
    const float* __restrict__ W, u16* __restrict__ Wt, int K, int N) {
  __shared__ float tile[32][33];
  const int k0 = blockIdx.x * 32, n0 = blockIdx.y * 32;
  const int tx = threadIdx.x & 31, ty = threadIdx.x >> 5;  // ty 0..7
#pragma unroll
  for (int i = 0; i < 4; ++i)
    tile[ty + i * 8][tx] = W[(size_t)(k0 + ty + i * 8) * N + n0 + tx];
  __syncthreads();
#pragma unroll
  for (int i = 0; i < 4; ++i)
    Wt[(size_t)(n0 + ty + i * 8) * K + k0 + tx] = f2bf(tile[tx][ty + i * 8]);
}

// ---------------- block reduce ----------------
__device__ __forceinline__ float blockSum(float v, float* sh) {
#pragma unroll
  for (int m = 32; m; m >>= 1) v += __shfl_xor(v, m);
  if ((threadIdx.x & 63) == 0) sh[threadIdx.x >> 6] = v;
  __syncthreads();
  return sh[0] + sh[1] + sh[2] + sh[3];
}

// ---------------- LN1: x[b, j] -> hw windowed/rolled bf16 [16][2048][768] ----------------
__global__ __launch_bounds__(256) void ln1_k(
    const float* __restrict__ x, const float* __restrict__ w,
    const float* __restrict__ b, u16* __restrict__ hw) {
  __shared__ float sh1[4], sh2[4];
  const int row = blockIdx.x;            // 0..32767 (b*2048 + i, rolled coords)
  const int bI = row >> 11, i = row & 2047;
  const int j = (i + 64) & 2047;         // source (unrolled) index
  const int tid = threadIdx.x;
  u16* dst = hw + (size_t)row * 768;
  if (j >= 2000) {                       // padded region -> zeros
    dst[tid] = 0; dst[tid + 256] = 0; dst[tid + 512] = 0;
    return;
  }
  const float* xr = x + ((size_t)bI * 2000 + j) * 768;
  float v0 = xr[tid], v1 = xr[tid + 256], v2 = xr[tid + 512];
  float mean = blockSum(v0 + v1 + v2, sh1) * (1.0f / 768.0f);
  float d0 = v0 - mean, d1 = v1 - mean, d2 = v2 - mean;
  float var = blockSum(d0 * d0 + d1 * d1 + d2 * d2, sh2) * (1.0f / 768.0f);
  float rs = rsqrtf(var + 1e-5f);
  dst[tid]       = f2bf(d0 * rs * w[tid]       + b[tid]);
  dst[tid + 256] = f2bf(d1 * rs * w[tid + 256] + b[tid + 256]);
  dst[tid + 512] = f2bf(d2 * rs * w[tid + 512] + b[tid + 512]);
}

// ---------------- LN2: x2 (f32, 32000 rows) -> h2 bf16 ----------------
__global__ __launch_bounds__(256) void ln2_k(
    const float* __restrict__ src, const float* __restrict__ w,
    const float* __restrict__ b, u16* __restrict__ dsth) {
  __shared__ float sh1[4], sh2[4];
  const int row = blockIdx.x;
  const int tid = threadIdx.x;
  const float* xr = src + (size_t)row * 768;
  u16* dst = dsth + (size_t)row * 768;
  float v0 = xr[tid], v1 = xr[tid + 256], v2 = xr[tid + 512];
  float mean = blockSum(v0 + v1 + v2, sh1) * (1.0f / 768.0f);
  float d0 = v0 - mean, d1 = v1 - mean, d2 = v2 - mean;
  float var = blockSum(d0 * d0 + d1 * d1 + d2 * d2, sh2) * (1.0f / 768.0f);
  float rs = rsqrtf(var + 1e-5f);
  dst[tid]       = f2bf(d0 * rs * w[tid]       + b[tid]);
  dst[tid + 256] = f2bf(d1 * rs * w[tid + 256] + b[tid + 256]);
  dst[tid + 512] = f2bf(d2 * rs * w[tid + 512] + b[tid + 512]);
}

// ================= 256x256 8-wave phase-split GEMM (2M x 4N waves) =================
// C = A[M,K] * Bt[N,K]^T. BK=64, 512 thr (8 waves), per-wave out 128x64.
// LDS: A dbuf [2][256][64] + B dbuf [2][256][64] bf16 = 128 KiB.
// XOR swizzle: byte ^= ((row&7)<<4) within each 128-B row.
enum { EQKV = 0, EPROJ = 1, EFC1 = 2, EFC2 = 3 };

__device__ __forceinline__ void stage_half(
    const u16* __restrict__ mat, int rowTileBase, int K, int k0,
    char* ldsbase /* op + buf + half */, int rl0, int kc) {
  const u16* s0 = mat + (size_t)(rowTileBase + rl0) * K + k0 + kc * 8;
  const u16* s1 = mat + (size_t)(rowTileBase + rl0 + 64) * K + k0 + kc * 8;
  const int wid = rl0 >> 3;  // tid>>6
  gload_lds16(s0, ldsbase + wid * 1024);
  gload_lds16(s1, ldsbase + 8192 + wid * 1024);
}

template <int EPI>
__global__ __launch_bounds__(512, 2) void gemm256(
    const u16* __restrict__ A, const u16* __restrict__ Bt,
    const float* __restrict__ bias, const float* __restrict__ lsv,
    const float* __restrict__ resid, float* __restrict__ outf,
    u16* __restrict__ outh, int gn, int N, int K, int mValid) {
  __shared__ u16 lds[65536];  // 128 KiB
  char* ldsc = (char*)lds;
  const int tid = threadIdx.x;
  const int lane = tid & 63, wid = tid >> 6;
  const int wr = wid >> 2, wc = wid & 3;  // 2M x 4N waves, each 128x64 out

  // bijective XCD swizzle (m204); nt-fast order -> A-panel stays in XCD L2
  const int nwg = gridDim.x, bid = blockIdx.x;
  const int q = nwg >> 3, r = nwg & 7;
  const int xcd = bid & 7, idx = bid >> 3;
  const int wg = (xcd < r ? xcd * (q + 1) : r * (q + 1) + (xcd - r) * q) + idx;
  const int mt = wg / gn, nt = wg % gn;
  const int m0 = mt * 256, n0 = nt * 256;
  const int NT = K >> 6;

  fx4 acc[8][4];
#pragma unroll
  for (int i = 0; i < 8; ++i)
#pragma unroll
    for (int j = 0; j < 4; ++j) acc[i][j] = fx4{0.f, 0.f, 0.f, 0.f};

  // read-side constants
  const int rsel = lane & 15, kgrp = lane >> 4;
  const int xorc = (rsel & 7) << 4;  // swizzle XOR is per-thread constant

  // stage-side constants: chunk = tid; row = tid>>3; kcol = (tid&7)^(row&7)
  const int rl0 = tid >> 3;
  const int kc = (tid & 7) ^ (rl0 & 7);  // row+64 keeps row&7 -> same kc

#define AOFF(buf, mi, kk) \
  ((buf)*32768 + (wr * 128 + (mi)*16 + rsel) * 128 + ((((kk)*64 + kgrp * 16)) ^ xorc))
#define BOFF(buf, ni, kk) \
  (65536 + (buf)*32768 + (wc * 64 + (ni)*16 + rsel) * 128 + ((((kk)*64 + kgrp * 16)) ^ xorc))

  // prologue: stage all 4 half-tiles of tile 0
  stage_half(A,  m0 +   0, K, 0, ldsc +          0 +     0, rl0, kc);
  stage_half(Bt, n0 +   0, K, 0, ldsc + 65536 +   0 +     0, rl0, kc);
  stage_half(Bt, n0 + 128, K, 0, ldsc + 65536 +   0 + 16384, rl0, kc);
  stage_half(A,  m0 + 128, K, 0, ldsc +          0 + 16384, rl0, kc);
  VMCNT(0);
  bar();

  for (int t = 0; t < NT; ++t) {
    const int buf = t & 1, nbuf = buf ^ 1;
    const int k1 = (t + 1) << 6;
    const bool more = (t + 1) < NT;
    bh8 af[4][2], bq[2][2];

#define READ_A(mh)                                                        \
  _Pragma("unroll") for (int m2 = 0; m2 < 4; ++m2)                        \
      _Pragma("unroll") for (int kk = 0; kk < 2; ++kk)                    \
          af[m2][kk] = *(const bh8*)(ldsc + AOFF(buf, (mh)*4 + m2, kk));
#define READ_B(nh)                                                        \
  _Pragma("unroll") for (int n2 = 0; n2 < 2; ++n2)                        \
      _Pragma("unroll") for (int kk = 0; kk < 2; ++kk)                    \
          bq[n2][kk] = *(const bh8*)(ldsc + BOFF(buf, (nh)*2 + n2, kk));
#define MFMA16(mh, nh)                                                    \
  __builtin_amdgcn_s_setprio(1);                                          \
  _Pragma("unroll") for (int m2 = 0; m2 < 4; ++m2)                        \
      _Pragma("unroll") for (int n2 = 0; n2 < 2; ++n2)                    \
          _Pragma("unroll") for (int kk = 0; kk < 2; ++kk)                \
              acc[(mh)*4 + m2][(nh)*2 + n2] =                             \
                  __builtin_amdgcn_mfma_f32_16x16x32_bf16(                \
                      af[m2][kk], bq[n2][kk], acc[(mh)*4 + m2][(nh)*2 + n2], 0, 0, 0); \
  __builtin_amdgcn_s_setprio(0);                                          \
  __builtin_amdgcn_sched_barrier(0);

    // ---- p0: reads A(0-3)+B(0-1); stage ALL 4 halves of tile t+1 ----
    READ_A(0);
    READ_B(0);
    if (more) {
      stage_half(A,  m0 +   0, K, k1, ldsc +         nbuf * 32768 +     0, rl0, kc);
      stage_half(Bt, n0 +   0, K, k1, ldsc + 65536 + nbuf * 32768 +     0, rl0, kc);
      stage_half(Bt, n0 + 128, K, k1, ldsc + 65536 + nbuf * 32768 + 16384, rl0, kc);
      stage_half(A,  m0 + 128, K, k1, ldsc +         nbuf * 32768 + 16384, rl0, kc);
    }
    bar();
    MFMA16(0, 0);
    bar();
    // ---- p1 ----
    READ_B(1);
    bar();
    MFMA16(0, 1);
    bar();
    // ---- p2 ----
    READ_A(1);
    READ_B(0);
    bar();
    MFMA16(1, 0);
    bar();
    // ---- p3 ----
    READ_B(1);
    bar();
    MFMA16(1, 1);
    if (more) { VMCNT(0); }  // tile t+1 fully staged (issued ~3.7 phases ago)
    bar();
#undef READ_A
#undef READ_B
#undef MFMA16
  }
#undef AOFF
#undef BOFF

  // epilogue; C/D layout: col = lane&15, row = (lane>>4)*4 + j   [m89-verified]
  const int cc = lane & 15;
  const int rq = (lane >> 4) * 4;
#pragma unroll
  for (int ni = 0; ni < 4; ++ni) {
    const int gc = n0 + wc * 64 + ni * 16 + cc;
    const float bv = bias[gc];
    const float ls = (EPI == EPROJ || EPI == EFC2) ? lsv[gc] : 0.f;
#pragma unroll
    for (int mi = 0; mi < 8; ++mi) {
#pragma unroll
      for (int j = 0; j < 4; ++j) {
        const int gr = m0 + wr * 128 + mi * 16 + rq + j;
        const float v = acc[mi][ni][j] + bv;
        if (EPI == EQKV) {
          outh[(size_t)gr * N + gc] = f2bf(v);
        } else if (EPI == EFC1) {
          const float t = 0.5f * v * (1.0f + erff(v * 0.70710678118654752f));
          outh[(size_t)gr * N + gc] = f2bf(t);
        } else if (EPI == EFC2) {
          if (gr < mValid) {
            const size_t o = (size_t)gr * 768 + gc;
            outf[o] += v * ls;
          }
        } else {  // EPROJ: unroll(+64), crop, x2 = x + a*ls1
          const int bI = gr >> 11, ip = gr & 2047;
          const int jj = (ip + 64) & 2047;
          if (jj < 2000) {
            const size_t o = ((size_t)bI * 2000 + jj) * 768 + gc;
            outf[o] = resid[o] + v * ls;
          }
        }
      }
    }
  }
}

// ---------------- window attention: one block per (window, head) ----------------
struct AttnLds {
  union {
    struct { u16 Qs[128][72]; u16 Ks[128][72]; } qk;  // 36864 B
    u16 Ps[128][136];                                  // 34816 B
  } u;
  u16 Vt[64][136];   // V^T: [d][kk], 17408 B
  float biasv[256];  // rel_bias column for this head
};

__global__ __launch_bounds__(256, 2) void attn_k(
    const u16* __restrict__ qkv, const float* __restrict__ rel_bias,
    u16* __restrict__ aout) {
  __shared__ AttnLds L;
  const int blk = blockIdx.x;
  const int w = blk / 12, h = blk - w * 12;
  const int wi = w & 15;  // window index within batch
  const int tid = threadIdx.x;
  const int lane = tid & 63, wid = tid >> 6;

  if (tid < 255) L.biasv[tid] = rel_bias[tid * 12 + h];

  const size_t rowbase = (size_t)w * 128;
#pragma unroll
  for (int i = 0; i < 4; ++i) {
    const int idx = tid + i * 256;          // 0..1023
    const int r = idx >> 3, seg = idx & 7;  // 128 rows x 8 segs of 8
    const u16* src = qkv + (rowbase + r) * 2304 + h * 64 + seg * 8;
    *(bh8*)&L.u.qk.Qs[r][seg * 8] = *(const bh8*)(src);
    *(bh8*)&L.u.qk.Ks[r][seg * 8] = *(const bh8*)(src + 768);
    bh8 vv = *(const bh8*)(src + 1536);
#pragma unroll
    for (int e = 0; e < 8; ++e) L.Vt[seg * 8 + e][r] = ((const u16*)&vv)[e];
  }
  __syncthreads();

  // QK^T: each wave owns 32 q-rows x all 128 k-cols
  const int R0 = wid * 32;
  const int rsel = lane & 15, kgrp = lane >> 4;
  fx4 s[2][8];
#pragma unroll
  for (int mi = 0; mi < 2; ++mi)
#pragma unroll
    for (int ni = 0; ni < 8; ++ni) s[mi][ni] = fx4{0.f, 0.f, 0.f, 0.f};

#pragma unroll
  for (int ks = 0; ks < 2; ++ks) {
    bh8 aq[2], bk[8];
#pragma unroll
    for (int mi = 0; mi < 2; ++mi)
      aq[mi] = *(const bh8*)&L.u.qk.Qs[R0 + mi * 16 + rsel][ks * 32 + kgrp * 8];
#pragma unroll
    for (int ni = 0; ni < 8; ++ni)
      bk[ni] = *(const bh8*)&L.u.qk.Ks[ni * 16 + rsel][ks * 32 + kgrp * 8];
#pragma unroll
    for (int mi = 0; mi < 2; ++mi)
#pragma unroll
      for (int ni = 0; ni < 8; ++ni)
        s[mi][ni] = __builtin_amdgcn_mfma_f32_16x16x32_bf16(aq[mi], bk[ni], s[mi][ni], 0, 0, 0);
  }

  // scale + rel-bias + mask + row softmax (rows live in a 16-lane group)
#pragma unroll
  for (int mi = 0; mi < 2; ++mi) {
#pragma unroll
    for (int j = 0; j < 4; ++j) {
      const int r = R0 + mi * 16 + kgrp * 4 + j;
      float vals[8];
      float mx = -1e30f;
#pragma unroll
      for (int ni = 0; ni < 8; ++ni) {
        const int c = ni * 16 + rsel;
        const int ic = wi * 128 + c;
        const bool valid = ((ic + 64) & 2047) < 2000;
        const float v = valid ? (s[mi][ni][j] * 0.125f + L.biasv[c - r + 127]) : -1e30f;
        vals[ni] = v;
        mx = fmaxf(mx, v);
      }
#pragma unroll
      for (int mm = 8; mm; mm >>= 1) mx = fmaxf(mx, __shfl_xor(mx, mm));
      float sum = 0.f;
#pragma unroll
      for (int ni = 0; ni < 8; ++ni) { float p = __expf(vals[ni] - mx); vals[ni] = p; sum += p; }
#pragma unroll
      for (int mm = 8; mm; mm >>= 1) sum += __shfl_xor(sum, mm);
      const float inv = 1.0f / sum;
#pragma unroll
      for (int ni = 0; ni < 8; ++ni) s[mi][ni][j] = vals[ni] * inv;
    }
  }
  __syncthreads();  // all QK^T LDS reads done before P overwrites Q/K (union)

#pragma unroll
  for (int mi = 0; mi < 2; ++mi)
#pragma unroll
    for (int ni = 0; ni < 8; ++ni)
#pragma unroll
      for (int j = 0; j < 4; ++j)
        L.u.Ps[R0 + mi * 16 + kgrp * 4 + j][ni * 16 + rsel] = f2bf(s[mi][ni][j]);
  __syncthreads();

  // PV: out 32x64 per wave
  fx4 o[2][4];
#pragma unroll
  for (int mi = 0; mi < 2; ++mi)
#pragma unroll
    for (int ni = 0; ni < 4; ++ni) o[mi][ni] = fx4{0.f, 0.f, 0.f, 0.f};
#pragma unroll
  for (int ks = 0; ks < 4; ++ks) {
    bh8 ap[2], bv[4];
#pragma unroll
    for (int mi = 0; mi < 2; ++mi)
      ap[mi] = *(const bh8*)&L.u.Ps[R0 + mi * 16 + rsel][ks * 32 + kgrp * 8];
#pragma unroll
    for (int ni = 0; ni < 4; ++ni)
      bv[ni] = *(const bh8*)&L.Vt[ni * 16 + rsel][ks * 32 + kgrp * 8];
#pragma unroll
    for (int mi = 0; mi < 2; ++mi)
#pragma unroll
      for (int ni = 0; ni < 4; ++ni)
        o[mi][ni] = __builtin_amdgcn_mfma_f32_16x16x32_bf16(ap[mi], bv[ni], o[mi][ni], 0, 0, 0);
  }

#pragma unroll
  for (int mi = 0; mi < 2; ++mi)
#pragma unroll
    for (int ni = 0; ni < 4; ++ni)
#pragma unroll
      for (int j = 0; j < 4; ++j)
        aout[(rowbase + R0 + mi * 16 + kgrp * 4 + j) * 768 + h * 64 + ni * 16 + rsel] =
            f2bf(o[mi][ni][j]);
}

// ---------------- host ----------------
extern "C" void kernel_launch(void* const* d_in, const int* in_sizes, int n_in,
                              void* d_out, int out_size, void* d_ws, size_t ws_size,
                              hipStream_t stream) {
  (void)in_sizes; (void)n_in; (void)out_size; (void)ws_size;
  const float* x        = (const float*)d_in[0];
  const float* n1w      = (const float*)d_in[1];
  const float* n1b      = (const float*)d_in[2];
  const float* qkv_w    = (const float*)d_in[3];
  const float* qkv_b    = (const float*)d_in[4];
  const float* proj_w   = (const float*)d_in[5];
  const float* proj_b   = (const float*)d_in[6];
  const float* rel_bias = (const float*)d_in[7];
  const float* ls1      = (const float*)d_in[8];
  const float* n2w      = (const float*)d_in[9];
  const float* n2b      = (const float*)d_in[10];
  const float* fc1_w    = (const float*)d_in[11];
  const float* fc1_b    = (const float*)d_in[12];
  const float* fc2_w    = (const float*)d_in[13];
  const float* fc2_b    = (const float*)d_in[14];
  const float* ls2      = (const float*)d_in[15];
  float* out = (float*)d_out;

  char* ws = (char*)d_ws;
  u16* WtQ  = (u16*)(ws);                                   //  768x2304^T : 3,538,944 B
  u16* WtP  = (u16*)(ws + 3538944);                         //  768x768^T  : 1,179,648 B
  u16* WtF1 = (u16*)(ws + 4718592);                         //  768x3072^T : 4,718,592 B
  u16* WtF2 = (u16*)(ws + 9437184);                         // 3072x768^T  : 4,718,592 B
  u16* bufB = (u16*)(ws + 14155776);                        // hw/attn/h2  : 50,331,648 B
  u16* bufA = (u16*)(ws + 14155776 + 50331648);             // qkv/g-half  : 150,994,944 B

  dim3 t256(256), t512(512);
  transp_cvt<<<dim3(24, 72), t256, 0, stream>>>(qkv_w, WtQ, 768, 2304);
  transp_cvt<<<dim3(24, 24), t256, 0, stream>>>(proj_w, WtP, 768, 768);
  transp_cvt<<<dim3(24, 96), t256, 0, stream>>>(fc1_w, WtF1, 768, 3072);
  transp_cvt<<<dim3(96, 24), t256, 0, stream>>>(fc2_w, WtF2, 3072, 768);

  ln1_k<<<32768, t256, 0, stream>>>(x, n1w, n1b, bufB);
  // QKV: M=32768, N=2304 (gn=9), K=768
  gemm256<EQKV><<<dim3(128 * 9), t512, 0, stream>>>(
      bufB, WtQ, qkv_b, nullptr, nullptr, nullptr, bufA, 9, 2304, 768, 32768);
  attn_k<<<3072, t256, 0, stream>>>(bufA, rel_bias, bufB);
  // PROJ: M=32768, N=768 (gn=3), K=768
  gemm256<EPROJ><<<dim3(128 * 3), t512, 0, stream>>>(
      bufB, WtP, proj_b, ls1, x, out, nullptr, 3, 768, 768, 32768);
  ln2_k<<<32000, t256, 0, stream>>>(out, n2w, n2b, bufB);
  for (int half = 0; half < 2; ++half) {
    const u16* h2h = bufB + (size_t)half * 16000 * 768;
    float* outh = out + (size_t)half * 16000 * 768;
    // FC1: M=16000 padded to 16128 (gm=63), N=3072 (gn=12), K=768
    gemm256<EFC1><<<dim3(63 * 12), t512, 0, stream>>>(
        h2h, WtF1, fc1_b, nullptr, nullptr, nullptr, bufA, 12, 3072, 768, 16128);
    // FC2: M=16000 padded (gm=63), N=768 (gn=3), K=3072; guard gr<16000
    gemm256<EFC2><<<dim3(63 * 3), t512, 0, stream>>>(
        bufA, WtF2, fc2_b, ls2, nullptr, outh, nullptr, 3, 768, 3072, 16000);
  }
}

// Round 4
// 997.577 us; speedup vs baseline: 1.0609x; 1.0609x over previous
//
#include <hip/hip_runtime.h>
#include <hip/hip_bf16.h>

typedef unsigned short u16;
typedef __attribute__((ext_vector_type(8))) short bh8;   // 8 x bf16 (4 VGPRs)
typedef __attribute__((ext_vector_type(4))) float fx4;   // MFMA accumulator

__device__ __forceinline__ u16 f2bf(float f) {
  union { float f; unsigned u; } v; v.f = f;
  unsigned r = v.u + 0x7FFFu + ((v.u >> 16) & 1u);  // RNE
  return (u16)(r >> 16);
}

__device__ __forceinline__ void gload_lds16(const void* g, void* l) {
  __builtin_amdgcn_global_load_lds(
      (const __attribute__((address_space(1))) void*)g,
      (__attribute__((address_space(3))) void*)l, 16, 0, 0);
}

#define VMCNT(n) asm volatile("s_waitcnt vmcnt(" #n ")" ::: "memory")

__device__ __forceinline__ void bar() {
  asm volatile("" ::: "memory");
  __builtin_amdgcn_sched_barrier(0);
  __builtin_amdgcn_s_barrier();
  __builtin_amdgcn_sched_barrier(0);
  asm volatile("" ::: "memory");
}

// ---------------- weight transpose + f32->bf16 : W[K][N] -> Wt[N][K] ----------------
__global__ __launch_bounds__(256) void transp_cvt(
    const float* __restrict__ W, u16* __restrict__ Wt, int K, int N) {
  __shared__ float tile[32][33];
  const int k0 = blockIdx.x * 32, n0 = blockIdx.y * 32;
  const int tx = threadIdx.x & 31, ty = threadIdx.x >> 5;  // ty 0..7
#pragma unroll
  for (int i = 0; i < 4; ++i)
    tile[ty + i * 8][tx] = W[(size_t)(k0 + ty + i * 8) * N + n0 + tx];
  __syncthreads();
#pragma unroll
  for (int i = 0; i < 4; ++i)
    Wt[(size_t)(n0 + ty + i * 8) * K + k0 + tx] = f2bf(tile[tx][ty + i * 8]);
}

// ---------------- block reduce ----------------
__device__ __forceinline__ float blockSum(float v, float* sh) {
#pragma unroll
  for (int m = 32; m; m >>= 1) v += __shfl_xor(v, m);
  if ((threadIdx.x & 63) == 0) sh[threadIdx.x >> 6] = v;
  __syncthreads();
  return sh[0] + sh[1] + sh[2] + sh[3];
}

// ---------------- LN1: x[b, j] -> hw windowed/rolled bf16 [16][2048][768] ----------------
__global__ __launch_bounds__(256) void ln1_k(
    const float* __restrict__ x, const float* __restrict__ w,
    const float* __restrict__ b, u16* __restrict__ hw) {
  __shared__ float sh1[4], sh2[4];
  const int row = blockIdx.x;            // 0..32767 (b*2048 + i, rolled coords)
  const int bI = row >> 11, i = row & 2047;
  const int j = (i + 64) & 2047;         // source (unrolled) index
  const int tid = threadIdx.x;
  u16* dst = hw + (size_t)row * 768;
  if (j >= 2000) {                       // padded region -> zeros
    dst[tid] = 0; dst[tid + 256] = 0; dst[tid + 512] = 0;
    return;
  }
  const float* xr = x + ((size_t)bI * 2000 + j) * 768;
  float v0 = xr[tid], v1 = xr[tid + 256], v2 = xr[tid + 512];
  float mean = blockSum(v0 + v1 + v2, sh1) * (1.0f / 768.0f);
  float d0 = v0 - mean, d1 = v1 - mean, d2 = v2 - mean;
  float var = blockSum(d0 * d0 + d1 * d1 + d2 * d2, sh2) * (1.0f / 768.0f);
  float rs = rsqrtf(var + 1e-5f);
  dst[tid]       = f2bf(d0 * rs * w[tid]       + b[tid]);
  dst[tid + 256] = f2bf(d1 * rs * w[tid + 256] + b[tid + 256]);
  dst[tid + 512] = f2bf(d2 * rs * w[tid + 512] + b[tid + 512]);
}

// ---------------- LN2: x2 (f32, 32000 rows) -> h2 bf16 ----------------
__global__ __launch_bounds__(256) void ln2_k(
    const float* __restrict__ src, const float* __restrict__ w,
    const float* __restrict__ b, u16* __restrict__ dsth) {
  __shared__ float sh1[4], sh2[4];
  const int row = blockIdx.x;
  const int tid = threadIdx.x;
  const float* xr = src + (size_t)row * 768;
  u16* dst = dsth + (size_t)row * 768;
  float v0 = xr[tid], v1 = xr[tid + 256], v2 = xr[tid + 512];
  float mean = blockSum(v0 + v1 + v2, sh1) * (1.0f / 768.0f);
  float d0 = v0 - mean, d1 = v1 - mean, d2 = v2 - mean;
  float var = blockSum(d0 * d0 + d1 * d1 + d2 * d2, sh2) * (1.0f / 768.0f);
  float rs = rsqrtf(var + 1e-5f);
  dst[tid]       = f2bf(d0 * rs * w[tid]       + b[tid]);
  dst[tid + 256] = f2bf(d1 * rs * w[tid + 256] + b[tid + 256]);
  dst[tid + 512] = f2bf(d2 * rs * w[tid + 512] + b[tid + 512]);
}

// ================= 256x256 8-wave phase-split GEMM (2M x 4N waves) =================
// C = A[M,K] * Bt[N,K]^T. BK=64, 512 thr (8 waves), per-wave out 128x64.
// LDS: A dbuf [2][256][64] + B dbuf [2][256][64] bf16 = 128 KiB.
// XOR swizzle: byte ^= ((row&7)<<4) within each 128-B row.
// Counted-vmcnt pipeline (T4): stage pairs at p0/p1, vmcnt(4) at p0-end &
// p3-end, never 0 in steady state.
enum { EQKV = 0, EPROJ = 1, EFC1 = 2, EFC2 = 3 };

__device__ __forceinline__ void stage_half(
    const u16* __restrict__ mat, int rowTileBase, int K, int k0,
    char* ldsbase /* op + buf + half */, int rl0, int kc) {
  const u16* s0 = mat + (size_t)(rowTileBase + rl0) * K + k0 + kc * 8;
  const u16* s1 = mat + (size_t)(rowTileBase + rl0 + 64) * K + k0 + kc * 8;
  const int wid = rl0 >> 3;  // tid>>6
  gload_lds16(s0, ldsbase + wid * 1024);
  gload_lds16(s1, ldsbase + 8192 + wid * 1024);
}

template <int EPI>
__global__ __launch_bounds__(512, 2) void gemm256(
    const u16* __restrict__ A, const u16* __restrict__ Bt,
    const float* __restrict__ bias, const float* __restrict__ lsv,
    const float* __restrict__ resid, float* __restrict__ outf,
    u16* __restrict__ outh, int gn, int N, int K, int mValid) {
  __shared__ u16 lds[65536];  // 128 KiB
  char* ldsc = (char*)lds;
  const int tid = threadIdx.x;
  const int lane = tid & 63, wid = tid >> 6;
  const int wr = wid >> 2, wc = wid & 3;  // 2M x 4N waves, each 128x64 out

  // bijective XCD swizzle (m204); nt-fast order -> A-panel stays in XCD L2
  const int nwg = gridDim.x, bid = blockIdx.x;
  const int q = nwg >> 3, r = nwg & 7;
  const int xcd = bid & 7, idx = bid >> 3;
  const int wg = (xcd < r ? xcd * (q + 1) : r * (q + 1) + (xcd - r) * q) + idx;
  const int mt = wg / gn, nt = wg % gn;
  const int m0 = mt * 256, n0 = nt * 256;
  const int NT = K >> 6;

  fx4 acc[8][4];
#pragma unroll
  for (int i = 0; i < 8; ++i)
#pragma unroll
    for (int j = 0; j < 4; ++j) acc[i][j] = fx4{0.f, 0.f, 0.f, 0.f};

  // read-side constants
  const int rsel = lane & 15, kgrp = lane >> 4;
  const int xorc = (rsel & 7) << 4;  // swizzle XOR is per-thread constant

  // stage-side constants: chunk = tid; row = tid>>3; kcol = (tid&7)^(row&7)
  const int rl0 = tid >> 3;
  const int kc = (tid & 7) ^ (rl0 & 7);  // row+64 keeps row&7 -> same kc

#define AOFF(buf, mi, kk) \
  ((buf)*32768 + (wr * 128 + (mi)*16 + rsel) * 128 + ((((kk)*64 + kgrp * 16)) ^ xorc))
#define BOFF(buf, ni, kk) \
  (65536 + (buf)*32768 + (wc * 64 + (ni)*16 + rsel) * 128 + ((((kk)*64 + kgrp * 16)) ^ xorc))

  // prologue: stage all 4 halves of tile 0 (issue order A0,B0,B1,A1)
  stage_half(A,  m0 +   0, K, 0, ldsc +          0 +     0, rl0, kc);
  stage_half(Bt, n0 +   0, K, 0, ldsc + 65536 +   0 +     0, rl0, kc);
  stage_half(Bt, n0 + 128, K, 0, ldsc + 65536 +   0 + 16384, rl0, kc);
  stage_half(A,  m0 + 128, K, 0, ldsc +          0 + 16384, rl0, kc);
  VMCNT(4);  // drains A0,B0; leaves B1,A1 in flight (like a t-1 p3-end)
  bar();

  for (int t = 0; t < NT; ++t) {
    const int buf = t & 1, nbuf = buf ^ 1;
    const int k1 = (t + 1) << 6;
    const bool more = (t + 1) < NT;
    bh8 af[4][2], bq[2][2];

#define READ_A(mh)                                                        \
  _Pragma("unroll") for (int m2 = 0; m2 < 4; ++m2)                        \
      _Pragma("unroll") for (int kk = 0; kk < 2; ++kk)                    \
          af[m2][kk] = *(const bh8*)(ldsc + AOFF(buf, (mh)*4 + m2, kk));
#define READ_B(nh)                                                        \
  _Pragma("unroll") for (int n2 = 0; n2 < 2; ++n2)                        \
      _Pragma("unroll") for (int kk = 0; kk < 2; ++kk)                    \
          bq[n2][kk] = *(const bh8*)(ldsc + BOFF(buf, (nh)*2 + n2, kk));
#define MFMA16(mh, nh)                                                    \
  __builtin_amdgcn_s_setprio(1);                                          \
  _Pragma("unroll") for (int m2 = 0; m2 < 4; ++m2)                        \
      _Pragma("unroll") for (int n2 = 0; n2 < 2; ++n2)                    \
          _Pragma("unroll") for (int kk = 0; kk < 2; ++kk)                \
              acc[(mh)*4 + m2][(nh)*2 + n2] =                             \
                  __builtin_amdgcn_mfma_f32_16x16x32_bf16(                \
                      af[m2][kk], bq[n2][kk], acc[(mh)*4 + m2][(nh)*2 + n2], 0, 0, 0); \
  __builtin_amdgcn_s_setprio(0);                                          \
  __builtin_amdgcn_sched_barrier(0);

    // ---- p0: reads A0,B0 (in LDS: guarded by prev p3-end wait+bar);
    //          stage A0',B0' of tile t+1 ----
    READ_A(0);
    READ_B(0);
    if (more) {
      stage_half(A,  m0 +   0, K, k1, ldsc +         nbuf * 32768 +     0, rl0, kc);
      stage_half(Bt, n0 +   0, K, k1, ldsc + 65536 + nbuf * 32768 +     0, rl0, kc);
    }
    bar();
    MFMA16(0, 0);
    // p0-end wait: drain B1(t),A1(t) (issued ~3.3 phases ago); keep A0',B0' in flight
    if (more) { VMCNT(4); } else { VMCNT(0); }
    bar();
    // ---- p1: reads B1; stage B1',A1' ----
    READ_B(1);
    if (more) {
      stage_half(Bt, n0 + 128, K, k1, ldsc + 65536 + nbuf * 32768 + 16384, rl0, kc);
      stage_half(A,  m0 + 128, K, k1, ldsc +         nbuf * 32768 + 16384, rl0, kc);
    }
    bar();
    MFMA16(0, 1);
    bar();
    // ---- p2: reads A1, B0 ----
    READ_A(1);
    READ_B(0);
    bar();
    MFMA16(1, 0);
    bar();
    // ---- p3: reads B1 ----
    READ_B(1);
    bar();
    MFMA16(1, 1);
    // p3-end wait: drain A0(t+1),B0(t+1) (issued ~3 phases ago); keep B1',A1'
    if (more) { VMCNT(4); }
    bar();
#undef READ_A
#undef READ_B
#undef MFMA16
  }
#undef AOFF
#undef BOFF

  // epilogue; C/D layout: col = lane&15, row = (lane>>4)*4 + j   [m89-verified]
  const int cc = lane & 15;
  const int rq = (lane >> 4) * 4;
#pragma unroll
  for (int ni = 0; ni < 4; ++ni) {
    const int gc = n0 + wc * 64 + ni * 16 + cc;
    const float bv = bias[gc];
    const float ls = (EPI == EPROJ || EPI == EFC2) ? lsv[gc] : 0.f;
#pragma unroll
    for (int mi = 0; mi < 8; ++mi) {
#pragma unroll
      for (int j = 0; j < 4; ++j) {
        const int gr = m0 + wr * 128 + mi * 16 + rq + j;
        const float v = acc[mi][ni][j] + bv;
        if (EPI == EQKV) {
          outh[(size_t)gr * N + gc] = f2bf(v);
        } else if (EPI == EFC1) {
          const float t = 0.5f * v * (1.0f + erff(v * 0.70710678118654752f));
          outh[(size_t)gr * N + gc] = f2bf(t);
        } else if (EPI == EFC2) {
          if (gr < mValid) {
            const size_t o = (size_t)gr * 768 + gc;
            outf[o] += v * ls;
          }
        } else {  // EPROJ: unroll(+64), crop, x2 = x + a*ls1
          const int bI = gr >> 11, ip = gr & 2047;
          const int jj = (ip + 64) & 2047;
          if (jj < 2000) {
            const size_t o = ((size_t)bI * 2000 + jj) * 768 + gc;
            outf[o] = resid[o] + v * ls;
          }
        }
      }
    }
  }
}

// ---------------- window attention: one block per (window, head) ----------------
struct AttnLds {
  union {
    struct { u16 Qs[128][72]; u16 Ks[128][72]; } qk;  // 36864 B
    u16 Ps[128][136];                                  // 34816 B
  } u;
  u16 Vt[64][136];   // V^T: [d][kk], 17408 B
  float biasv[256];  // rel_bias column for this head
};

__global__ __launch_bounds__(256, 2) void attn_k(
    const u16* __restrict__ qkv, const float* __restrict__ rel_bias,
    u16* __restrict__ aout) {
  __shared__ AttnLds L;
  const int blk = blockIdx.x;
  const int w = blk / 12, h = blk - w * 12;
  const int wi = w & 15;  // window index within batch
  const int tid = threadIdx.x;
  const int lane = tid & 63, wid = tid >> 6;

  if (tid < 255) L.biasv[tid] = rel_bias[tid * 12 + h];

  const size_t rowbase = (size_t)w * 128;
#pragma unroll
  for (int i = 0; i < 4; ++i) {
    const int idx = tid + i * 256;          // 0..1023
    const int r = idx >> 3, seg = idx & 7;  // 128 rows x 8 segs of 8
    const u16* src = qkv + (rowbase + r) * 2304 + h * 64 + seg * 8;
    *(bh8*)&L.u.qk.Qs[r][seg * 8] = *(const bh8*)(src);
    *(bh8*)&L.u.qk.Ks[r][seg * 8] = *(const bh8*)(src + 768);
    bh8 vv = *(const bh8*)(src + 1536);
#pragma unroll
    for (int e = 0; e < 8; ++e) L.Vt[seg * 8 + e][r] = ((const u16*)&vv)[e];
  }
  __syncthreads();

  // QK^T: each wave owns 32 q-rows x all 128 k-cols
  const int R0 = wid * 32;
  const int rsel = lane & 15, kgrp = lane >> 4;
  fx4 s[2][8];
#pragma unroll
  for (int mi = 0; mi < 2; ++mi)
#pragma unroll
    for (int ni = 0; ni < 8; ++ni) s[mi][ni] = fx4{0.f, 0.f, 0.f, 0.f};

#pragma unroll
  for (int ks = 0; ks < 2; ++ks) {
    bh8 aq[2], bk[8];
#pragma unroll
    for (int mi = 0; mi < 2; ++mi)
      aq[mi] = *(const bh8*)&L.u.qk.Qs[R0 + mi * 16 + rsel][ks * 32 + kgrp * 8];
#pragma unroll
    for (int ni = 0; ni < 8; ++ni)
      bk[ni] = *(const bh8*)&L.u.qk.Ks[ni * 16 + rsel][ks * 32 + kgrp * 8];
#pragma unroll
    for (int mi = 0; mi < 2; ++mi)
#pragma unroll
      for (int ni = 0; ni < 8; ++ni)
        s[mi][ni] = __builtin_amdgcn_mfma_f32_16x16x32_bf16(aq[mi], bk[ni], s[mi][ni], 0, 0, 0);
  }

  // scale + rel-bias + mask + row softmax (rows live in a 16-lane group)
#pragma unroll
  for (int mi = 0; mi < 2; ++mi) {
#pragma unroll
    for (int j = 0; j < 4; ++j) {
      const int r = R0 + mi * 16 + kgrp * 4 + j;
      float vals[8];
      float mx = -1e30f;
#pragma unroll
      for (int ni = 0; ni < 8; ++ni) {
        const int c = ni * 16 + rsel;
        const int ic = wi * 128 + c;
        const bool valid = ((ic + 64) & 2047) < 2000;
        const float v = valid ? (s[mi][ni][j] * 0.125f + L.biasv[c - r + 127]) : -1e30f;
        vals[ni] = v;
        mx = fmaxf(mx, v);
      }
#pragma unroll
      for (int mm = 8; mm; mm >>= 1) mx = fmaxf(mx, __shfl_xor(mx, mm));
      float sum = 0.f;
#pragma unroll
      for (int ni = 0; ni < 8; ++ni) { float p = __expf(vals[ni] - mx); vals[ni] = p; sum += p; }
#pragma unroll
      for (int mm = 8; mm; mm >>= 1) sum += __shfl_xor(sum, mm);
      const float inv = 1.0f / sum;
#pragma unroll
      for (int ni = 0; ni < 8; ++ni) s[mi][ni][j] = vals[ni] * inv;
    }
  }
  __syncthreads();  // all QK^T LDS reads done before P overwrites Q/K (union)

#pragma unroll
  for (int mi = 0; mi < 2; ++mi)
#pragma unroll
    for (int ni = 0; ni < 8; ++ni)
#pragma unroll
      for (int j = 0; j < 4; ++j)
        L.u.Ps[R0 + mi * 16 + kgrp * 4 + j][ni * 16 + rsel] = f2bf(s[mi][ni][j]);
  __syncthreads();

  // PV: out 32x64 per wave
  fx4 o[2][4];
#pragma unroll
  for (int mi = 0; mi < 2; ++mi)
#pragma unroll
    for (int ni = 0; ni < 4; ++ni) o[mi][ni] = fx4{0.f, 0.f, 0.f, 0.f};
#pragma unroll
  for (int ks = 0; ks < 4; ++ks) {
    bh8 ap[2], bv[4];
#pragma unroll
    for (int mi = 0; mi < 2; ++mi)
      ap[mi] = *(const bh8*)&L.u.Ps[R0 + mi * 16 + rsel][ks * 32 + kgrp * 8];
#pragma unroll
    for (int ni = 0; ni < 4; ++ni)
      bv[ni] = *(const bh8*)&L.Vt[ni * 16 + rsel][ks * 32 + kgrp * 8];
#pragma unroll
    for (int mi = 0; mi < 2; ++mi)
#pragma unroll
      for (int ni = 0; ni < 4; ++ni)
        o[mi][ni] = __builtin_amdgcn_mfma_f32_16x16x32_bf16(ap[mi], bv[ni], o[mi][ni], 0, 0, 0);
  }

#pragma unroll
  for (int mi = 0; mi < 2; ++mi)
#pragma unroll
    for (int ni = 0; ni < 4; ++ni)
#pragma unroll
      for (int j = 0; j < 4; ++j)
        aout[(rowbase + R0 + mi * 16 + kgrp * 4 + j) * 768 + h * 64 + ni * 16 + rsel] =
            f2bf(o[mi][ni][j]);
}

// ---------------- host ----------------
extern "C" void kernel_launch(void* const* d_in, const int* in_sizes, int n_in,
                              void* d_out, int out_size, void* d_ws, size_t ws_size,
                              hipStream_t stream) {
  (void)in_sizes; (void)n_in; (void)out_size; (void)ws_size;
  const float* x        = (const float*)d_in[0];
  const float* n1w      = (const float*)d_in[1];
  const float* n1b      = (const float*)d_in[2];
  const float* qkv_w    = (const float*)d_in[3];
  const float* qkv_b    = (const float*)d_in[4];
  const float* proj_w   = (const float*)d_in[5];
  const float* proj_b   = (const float*)d_in[6];
  const float* rel_bias = (const float*)d_in[7];
  const float* ls1      = (const float*)d_in[8];
  const float* n2w      = (const float*)d_in[9];
  const float* n2b      = (const float*)d_in[10];
  const float* fc1_w    = (const float*)d_in[11];
  const float* fc1_b    = (const float*)d_in[12];
  const float* fc2_w    = (const float*)d_in[13];
  const float* fc2_b    = (const float*)d_in[14];
  const float* ls2      = (const float*)d_in[15];
  float* out = (float*)d_out;

  char* ws = (char*)d_ws;
  u16* WtQ  = (u16*)(ws);                                   //  768x2304^T : 3,538,944 B
  u16* WtP  = (u16*)(ws + 3538944);                         //  768x768^T  : 1,179,648 B
  u16* WtF1 = (u16*)(ws + 4718592);                         //  768x3072^T : 4,718,592 B
  u16* WtF2 = (u16*)(ws + 9437184);                         // 3072x768^T  : 4,718,592 B
  u16* bufB = (u16*)(ws + 14155776);                        // hw/attn/h2  : 50,331,648 B
  u16* bufA = (u16*)(ws + 14155776 + 50331648);             // qkv/g-half  : 150,994,944 B

  dim3 t256(256), t512(512);
  transp_cvt<<<dim3(24, 72), t256, 0, stream>>>(qkv_w, WtQ, 768, 2304);
  transp_cvt<<<dim3(24, 24), t256, 0, stream>>>(proj_w, WtP, 768, 768);
  transp_cvt<<<dim3(24, 96), t256, 0, stream>>>(fc1_w, WtF1, 768, 3072);
  transp_cvt<<<dim3(96, 24), t256, 0, stream>>>(fc2_w, WtF2, 3072, 768);

  ln1_k<<<32768, t256, 0, stream>>>(x, n1w, n1b, bufB);
  // QKV: M=32768, N=2304 (gn=9), K=768
  gemm256<EQKV><<<dim3(128 * 9), t512, 0, stream>>>(
      bufB, WtQ, qkv_b, nullptr, nullptr, nullptr, bufA, 9, 2304, 768, 32768);
  attn_k<<<3072, t256, 0, stream>>>(bufA, rel_bias, bufB);
  // PROJ: M=32768, N=768 (gn=3), K=768
  gemm256<EPROJ><<<dim3(128 * 3), t512, 0, stream>>>(
      bufB, WtP, proj_b, ls1, x, out, nullptr, 3, 768, 768, 32768);
  ln2_k<<<32000, t256, 0, stream>>>(out, n2w, n2b, bufB);
  for (int half = 0; half < 2; ++half) {
    const u16* h2h = bufB + (size_t)half * 16000 * 768;
    float* outh = out + (size_t)half * 16000 * 768;
    // FC1: M=16000 padded to 16128 (gm=63), N=3072 (gn=12), K=768
    gemm256<EFC1><<<dim3(63 * 12), t512, 0, stream>>>(
        h2h, WtF1, fc1_b, nullptr, nullptr, nullptr, bufA, 12, 3072, 768, 16128);
    // FC2: M=16000 padded (gm=63), N=768 (gn=3), K=3072; guard gr<16000
    gemm256<EFC2><<<dim3(63 * 3), t512, 0, stream>>>(
        bufA, WtF2, fc2_b, ls2, nullptr, outh, nullptr, 3, 768, 3072, 16000);
  }
}

// Round 5
// 871.424 us; speedup vs baseline: 1.2145x; 1.1448x over previous
//
#include <hip/hip_runtime.h>
#include <hip/hip_bf16.h>

typedef unsigned short u16;
typedef __attribute__((ext_vector_type(8))) short bh8;   // 8 x bf16 (4 VGPRs)
typedef __attribute__((ext_vector_type(4))) float fx4;   // MFMA accumulator

__device__ __forceinline__ u16 f2bf(float f) {
  union { float f; unsigned u; } v; v.f = f;
  unsigned r = v.u + 0x7FFFu + ((v.u >> 16) & 1u);  // RNE
  return (u16)(r >> 16);
}

__device__ __forceinline__ void gload_lds16(const void* g, void* l) {
  __builtin_amdgcn_global_load_lds(
      (const __attribute__((address_space(1))) void*)g,
      (__attribute__((address_space(3))) void*)l, 16, 0, 0);
}

// ---------------- weight transpose + f32->bf16 : W[K][N] -> Wt[N][K] ----------------
__global__ __launch_bounds__(256) void transp_cvt(
    const float* __restrict__ W, u16* __restrict__ Wt, int K, int N) {
  __shared__ float tile[32][33];
  const int k0 = blockIdx.x * 32, n0 = blockIdx.y * 32;
  const int tx = threadIdx.x & 31, ty = threadIdx.x >> 5;  // ty 0..7
#pragma unroll
  for (int i = 0; i < 4; ++i)
    tile[ty + i * 8][tx] = W[(size_t)(k0 + ty + i * 8) * N + n0 + tx];
  __syncthreads();
#pragma unroll
  for (int i = 0; i < 4; ++i)
    Wt[(size_t)(n0 + ty + i * 8) * K + k0 + tx] = f2bf(tile[tx][ty + i * 8]);
}

// ---------------- block reduce ----------------
__device__ __forceinline__ float blockSum(float v, float* sh) {
#pragma unroll
  for (int m = 32; m; m >>= 1) v += __shfl_xor(v, m);
  if ((threadIdx.x & 63) == 0) sh[threadIdx.x >> 6] = v;
  __syncthreads();
  return sh[0] + sh[1] + sh[2] + sh[3];
}

// ---------------- LN1: x[b, j] -> hw windowed/rolled bf16 [16][2048][768] ----------------
__global__ __launch_bounds__(256) void ln1_k(
    const float* __restrict__ x, const float* __restrict__ w,
    const float* __restrict__ b, u16* __restrict__ hw) {
  __shared__ float sh1[4], sh2[4];
  const int row = blockIdx.x;            // 0..32767 (b*2048 + i, rolled coords)
  const int bI = row >> 11, i = row & 2047;
  const int j = (i + 64) & 2047;         // source (unrolled) index
  const int tid = threadIdx.x;
  u16* dst = hw + (size_t)row * 768;
  if (j >= 2000) {                       // padded region -> zeros
    dst[tid] = 0; dst[tid + 256] = 0; dst[tid + 512] = 0;
    return;
  }
  const float* xr = x + ((size_t)bI * 2000 + j) * 768;
  float v0 = xr[tid], v1 = xr[tid + 256], v2 = xr[tid + 512];
  float mean = blockSum(v0 + v1 + v2, sh1) * (1.0f / 768.0f);
  float d0 = v0 - mean, d1 = v1 - mean, d2 = v2 - mean;
  float var = blockSum(d0 * d0 + d1 * d1 + d2 * d2, sh2) * (1.0f / 768.0f);
  float rs = rsqrtf(var + 1e-5f);
  dst[tid]       = f2bf(d0 * rs * w[tid]       + b[tid]);
  dst[tid + 256] = f2bf(d1 * rs * w[tid + 256] + b[tid + 256]);
  dst[tid + 512] = f2bf(d2 * rs * w[tid + 512] + b[tid + 512]);
}

// ---------------- LN2: x2 (f32, 32000 rows) -> h2 bf16 ----------------
__global__ __launch_bounds__(256) void ln2_k(
    const float* __restrict__ src, const float* __restrict__ w,
    const float* __restrict__ b, u16* __restrict__ dsth) {
  __shared__ float sh1[4], sh2[4];
  const int row = blockIdx.x;
  const int tid = threadIdx.x;
  const float* xr = src + (size_t)row * 768;
  u16* dst = dsth + (size_t)row * 768;
  float v0 = xr[tid], v1 = xr[tid + 256], v2 = xr[tid + 512];
  float mean = blockSum(v0 + v1 + v2, sh1) * (1.0f / 768.0f);
  float d0 = v0 - mean, d1 = v1 - mean, d2 = v2 - mean;
  float var = blockSum(d0 * d0 + d1 * d1 + d2 * d2, sh2) * (1.0f / 768.0f);
  float rs = rsqrtf(var + 1e-5f);
  dst[tid]       = f2bf(d0 * rs * w[tid]       + b[tid]);
  dst[tid + 256] = f2bf(d1 * rs * w[tid + 256] + b[tid + 256]);
  dst[tid + 512] = f2bf(d2 * rs * w[tid + 512] + b[tid + 512]);
}

// ================= 128x128 m97-style GEMM, BK=64, swizzled LDS =================
// C = A[M,K] * Bt[N,K]^T. 256 thr (4 waves, 2x2), per-wave out 64x64.
// LDS: As[128][64] + Bs[128][64] bf16 = 32 KiB, single-buffered.
// T2 swizzle: read byte ^= ((row&7)<<4); staged via pre-swizzled global src.
enum { EQKV = 0, EPROJ = 1, EFC1 = 2, EFC2 = 3 };

template <int EPI>
__global__ __launch_bounds__(256, 4) void gemm128(
    const u16* __restrict__ A, const u16* __restrict__ Bt,
    const float* __restrict__ bias, const float* __restrict__ lsv,
    const float* __restrict__ resid, float* __restrict__ outf,
    u16* __restrict__ outh, int gn, int N, int K, int mValid) {
  __shared__ u16 As[8192];  // [128][64]
  __shared__ u16 Bs[8192];
  const int tid = threadIdx.x;
  const int lane = tid & 63, wid = tid >> 6;
  const int wr = wid >> 1, wc = wid & 1;  // 2x2 waves, 64x64 each

  // bijective XCD swizzle (m204); nt-fast order -> A-panel stays in XCD L2
  const int nwg = gridDim.x, bid = blockIdx.x;
  const int q = nwg >> 3, r = nwg & 7;
  const int xcd = bid & 7, idx = bid >> 3;
  const int wg = (xcd < r ? xcd * (q + 1) : r * (q + 1) + (xcd - r) * q) + idx;
  const int mt = wg / gn, nt = wg % gn;
  const int m0 = mt * 128, n0 = nt * 128;
  const int NT = K >> 6;

  fx4 acc[4][4];
#pragma unroll
  for (int i = 0; i < 4; ++i)
#pragma unroll
    for (int j = 0; j < 4; ++j) acc[i][j] = fx4{0.f, 0.f, 0.f, 0.f};

  // read-side constants
  const int rsel = lane & 15, kgrp = lane >> 4;
  const int xorc = (rsel & 7) << 4;  // per-thread constant swizzle XOR

  // stage-side: thread t stages rows rl, rl+32, rl+64, rl+96; 16B chunk
  // (tid&7) of each 128B row, source col pre-swizzled so linear LDS write +
  // XOR'd read reconstructs row-major (both-sides rule, m231).
  const int rl = tid >> 3;                       // 0..31
  const int kc8 = ((tid & 7) ^ (rl & 7)) * 8;    // source k element offset
  const u16* aRow = A + (size_t)(m0 + rl) * K + kc8;
  const u16* bRow = Bt + (size_t)(n0 + rl) * K + kc8;
  char* aDst = (char*)As + wid * 1024;  // wave-uniform base; +lane*16 implied
  char* bDst = (char*)Bs + wid * 1024;

  for (int t = 0; t < NT; ++t) {
    const int k0 = t << 6;
#pragma unroll
    for (int i = 0; i < 4; ++i) {
      gload_lds16(aRow + k0 + (size_t)(i * 32) * K, aDst + i * 4096);
      gload_lds16(bRow + k0 + (size_t)(i * 32) * K, bDst + i * 4096);
    }
    __syncthreads();  // compiler emits vmcnt(0) drain here (m97 semantics)
#pragma unroll
    for (int kk = 0; kk < 2; ++kk) {
      bh8 af[4], bf[4];
#pragma unroll
      for (int mi = 0; mi < 4; ++mi)
        af[mi] = *(const bh8*)((char*)As + (wr * 64 + mi * 16 + rsel) * 128 +
                               ((kk * 64 + kgrp * 16) ^ xorc));
#pragma unroll
      for (int ni = 0; ni < 4; ++ni)
        bf[ni] = *(const bh8*)((char*)Bs + (wc * 64 + ni * 16 + rsel) * 128 +
                               ((kk * 64 + kgrp * 16) ^ xorc));
#pragma unroll
      for (int mi = 0; mi < 4; ++mi)
#pragma unroll
        for (int ni = 0; ni < 4; ++ni)
          acc[mi][ni] = __builtin_amdgcn_mfma_f32_16x16x32_bf16(
              af[mi], bf[ni], acc[mi][ni], 0, 0, 0);
    }
    __syncthreads();
  }

  // epilogue; C/D layout: col = lane&15, row = (lane>>4)*4 + j   [m89-verified]
  const int cc = lane & 15;
  const int rq = (lane >> 4) * 4;
#pragma unroll
  for (int ni = 0; ni < 4; ++ni) {
    const int gc = n0 + wc * 64 + ni * 16 + cc;
    const float bv = bias[gc];
    const float ls = (EPI == EPROJ || EPI == EFC2) ? lsv[gc] : 0.f;
#pragma unroll
    for (int mi = 0; mi < 4; ++mi) {
#pragma unroll
      for (int j = 0; j < 4; ++j) {
        const int gr = m0 + wr * 64 + mi * 16 + rq + j;
        const float v = acc[mi][ni][j] + bv;
        if (EPI == EQKV) {
          outh[(size_t)gr * N + gc] = f2bf(v);
        } else if (EPI == EFC1) {
          const float t2 = 0.5f * v * (1.0f + erff(v * 0.70710678118654752f));
          outh[(size_t)gr * N + gc] = f2bf(t2);
        } else if (EPI == EFC2) {
          if (gr < mValid) {
            const size_t o = (size_t)gr * 768 + gc;
            outf[o] += v * ls;
          }
        } else {  // EPROJ: unroll(+64), crop, x2 = x + a*ls1
          const int bI = gr >> 11, ip = gr & 2047;
          const int jj = (ip + 64) & 2047;
          if (jj < 2000) {
            const size_t o = ((size_t)bI * 2000 + jj) * 768 + gc;
            outf[o] = resid[o] + v * ls;
          }
        }
      }
    }
  }
}

// ---------------- window attention: one block per (window, head) ----------------
struct AttnLds {
  union {
    struct { u16 Qs[128][72]; u16 Ks[128][72]; } qk;  // 36864 B
    u16 Ps[128][136];                                  // 34816 B
  } u;
  u16 Vt[64][136];   // V^T: [d][kk], 17408 B
  float biasv[256];  // rel_bias column for this head
};

__global__ __launch_bounds__(256, 2) void attn_k(
    const u16* __restrict__ qkv, const float* __restrict__ rel_bias,
    u16* __restrict__ aout) {
  __shared__ AttnLds L;
  const int blk = blockIdx.x;
  const int w = blk / 12, h = blk - w * 12;
  const int wi = w & 15;  // window index within batch
  const int tid = threadIdx.x;
  const int lane = tid & 63, wid = tid >> 6;

  if (tid < 255) L.biasv[tid] = rel_bias[tid * 12 + h];

  const size_t rowbase = (size_t)w * 128;
#pragma unroll
  for (int i = 0; i < 4; ++i) {
    const int idx = tid + i * 256;          // 0..1023
    const int r = idx >> 3, seg = idx & 7;  // 128 rows x 8 segs of 8
    const u16* src = qkv + (rowbase + r) * 2304 + h * 64 + seg * 8;
    *(bh8*)&L.u.qk.Qs[r][seg * 8] = *(const bh8*)(src);
    *(bh8*)&L.u.qk.Ks[r][seg * 8] = *(const bh8*)(src + 768);
    bh8 vv = *(const bh8*)(src + 1536);
#pragma unroll
    for (int e = 0; e < 8; ++e) L.Vt[seg * 8 + e][r] = ((const u16*)&vv)[e];
  }
  __syncthreads();

  // QK^T: each wave owns 32 q-rows x all 128 k-cols
  const int R0 = wid * 32;
  const int rsel = lane & 15, kgrp = lane >> 4;
  fx4 s[2][8];
#pragma unroll
  for (int mi = 0; mi < 2; ++mi)
#pragma unroll
    for (int ni = 0; ni < 8; ++ni) s[mi][ni] = fx4{0.f, 0.f, 0.f, 0.f};

#pragma unroll
  for (int ks = 0; ks < 2; ++ks) {
    bh8 aq[2], bk[8];
#pragma unroll
    for (int mi = 0; mi < 2; ++mi)
      aq[mi] = *(const bh8*)&L.u.qk.Qs[R0 + mi * 16 + rsel][ks * 32 + kgrp * 8];
#pragma unroll
    for (int ni = 0; ni < 8; ++ni)
      bk[ni] = *(const bh8*)&L.u.qk.Ks[ni * 16 + rsel][ks * 32 + kgrp * 8];
#pragma unroll
    for (int mi = 0; mi < 2; ++mi)
#pragma unroll
      for (int ni = 0; ni < 8; ++ni)
        s[mi][ni] = __builtin_amdgcn_mfma_f32_16x16x32_bf16(aq[mi], bk[ni], s[mi][ni], 0, 0, 0);
  }

  // scale + rel-bias + mask + row softmax (rows live in a 16-lane group)
#pragma unroll
  for (int mi = 0; mi < 2; ++mi) {
#pragma unroll
    for (int j = 0; j < 4; ++j) {
      const int r = R0 + mi * 16 + kgrp * 4 + j;
      float vals[8];
      float mx = -1e30f;
#pragma unroll
      for (int ni = 0; ni < 8; ++ni) {
        const int c = ni * 16 + rsel;
        const int ic = wi * 128 + c;
        const bool valid = ((ic + 64) & 2047) < 2000;
        const float v = valid ? (s[mi][ni][j] * 0.125f + L.biasv[c - r + 127]) : -1e30f;
        vals[ni] = v;
        mx = fmaxf(mx, v);
      }
#pragma unroll
      for (int mm = 8; mm; mm >>= 1) mx = fmaxf(mx, __shfl_xor(mx, mm));
      float sum = 0.f;
#pragma unroll
      for (int ni = 0; ni < 8; ++ni) { float p = __expf(vals[ni] - mx); vals[ni] = p; sum += p; }
#pragma unroll
      for (int mm = 8; mm; mm >>= 1) sum += __shfl_xor(sum, mm);
      const float inv = 1.0f / sum;
#pragma unroll
      for (int ni = 0; ni < 8; ++ni) s[mi][ni][j] = vals[ni] * inv;
    }
  }
  __syncthreads();  // all QK^T LDS reads done before P overwrites Q/K (union)

#pragma unroll
  for (int mi = 0; mi < 2; ++mi)
#pragma unroll
    for (int ni = 0; ni < 8; ++ni)
#pragma unroll
      for (int j = 0; j < 4; ++j)
        L.u.Ps[R0 + mi * 16 + kgrp * 4 + j][ni * 16 + rsel] = f2bf(s[mi][ni][j]);
  __syncthreads();

  // PV: out 32x64 per wave
  fx4 o[2][4];
#pragma unroll
  for (int mi = 0; mi < 2; ++mi)
#pragma unroll
    for (int ni = 0; ni < 4; ++ni) o[mi][ni] = fx4{0.f, 0.f, 0.f, 0.f};
#pragma unroll
  for (int ks = 0; ks < 4; ++ks) {
    bh8 ap[2], bv[4];
#pragma unroll
    for (int mi = 0; mi < 2; ++mi)
      ap[mi] = *(const bh8*)&L.u.Ps[R0 + mi * 16 + rsel][ks * 32 + kgrp * 8];
#pragma unroll
    for (int ni = 0; ni < 4; ++ni)
      bv[ni] = *(const bh8*)&L.Vt[ni * 16 + rsel][ks * 32 + kgrp * 8];
#pragma unroll
    for (int mi = 0; mi < 2; ++mi)
#pragma unroll
      for (int ni = 0; ni < 4; ++ni)
        o[mi][ni] = __builtin_amdgcn_mfma_f32_16x16x32_bf16(ap[mi], bv[ni], o[mi][ni], 0, 0, 0);
  }

#pragma unroll
  for (int mi = 0; mi < 2; ++mi)
#pragma unroll
    for (int ni = 0; ni < 4; ++ni)
#pragma unroll
      for (int j = 0; j < 4; ++j)
        aout[(rowbase + R0 + mi * 16 + kgrp * 4 + j) * 768 + h * 64 + ni * 16 + rsel] =
            f2bf(o[mi][ni][j]);
}

// ---------------- host ----------------
extern "C" void kernel_launch(void* const* d_in, const int* in_sizes, int n_in,
                              void* d_out, int out_size, void* d_ws, size_t ws_size,
                              hipStream_t stream) {
  (void)in_sizes; (void)n_in; (void)out_size; (void)ws_size;
  const float* x        = (const float*)d_in[0];
  const float* n1w      = (const float*)d_in[1];
  const float* n1b      = (const float*)d_in[2];
  const float* qkv_w    = (const float*)d_in[3];
  const float* qkv_b    = (const float*)d_in[4];
  const float* proj_w   = (const float*)d_in[5];
  const float* proj_b   = (const float*)d_in[6];
  const float* rel_bias = (const float*)d_in[7];
  const float* ls1      = (const float*)d_in[8];
  const float* n2w      = (const float*)d_in[9];
  const float* n2b      = (const float*)d_in[10];
  const float* fc1_w    = (const float*)d_in[11];
  const float* fc1_b    = (const float*)d_in[12];
  const float* fc2_w    = (const float*)d_in[13];
  const float* fc2_b    = (const float*)d_in[14];
  const float* ls2      = (const float*)d_in[15];
  float* out = (float*)d_out;

  char* ws = (char*)d_ws;
  u16* WtQ  = (u16*)(ws);                                   //  768x2304^T : 3,538,944 B
  u16* WtP  = (u16*)(ws + 3538944);                         //  768x768^T  : 1,179,648 B
  u16* WtF1 = (u16*)(ws + 4718592);                         //  768x3072^T : 4,718,592 B
  u16* WtF2 = (u16*)(ws + 9437184);                         // 3072x768^T  : 4,718,592 B
  u16* bufB = (u16*)(ws + 14155776);                        // hw/attn/h2  : 50,331,648 B
  u16* bufA = (u16*)(ws + 14155776 + 50331648);             // qkv/g-half  : 150,994,944 B

  dim3 t256(256);
  transp_cvt<<<dim3(24, 72), t256, 0, stream>>>(qkv_w, WtQ, 768, 2304);
  transp_cvt<<<dim3(24, 24), t256, 0, stream>>>(proj_w, WtP, 768, 768);
  transp_cvt<<<dim3(24, 96), t256, 0, stream>>>(fc1_w, WtF1, 768, 3072);
  transp_cvt<<<dim3(96, 24), t256, 0, stream>>>(fc2_w, WtF2, 3072, 768);

  ln1_k<<<32768, t256, 0, stream>>>(x, n1w, n1b, bufB);
  // QKV: M=32768 (256 mt), N=2304 (gn=18), K=768
  gemm128<EQKV><<<dim3(256 * 18), t256, 0, stream>>>(
      bufB, WtQ, qkv_b, nullptr, nullptr, nullptr, bufA, 18, 2304, 768, 32768);
  attn_k<<<3072, t256, 0, stream>>>(bufA, rel_bias, bufB);
  // PROJ: M=32768, N=768 (gn=6), K=768
  gemm128<EPROJ><<<dim3(256 * 6), t256, 0, stream>>>(
      bufB, WtP, proj_b, ls1, x, out, nullptr, 6, 768, 768, 32768);
  ln2_k<<<32000, t256, 0, stream>>>(out, n2w, n2b, bufB);
  for (int half = 0; half < 2; ++half) {
    const u16* h2h = bufB + (size_t)half * 16000 * 768;
    float* outh = out + (size_t)half * 16000 * 768;
    // FC1: M=16000 padded to 16128 (126 mt), N=3072 (gn=24), K=768
    gemm128<EFC1><<<dim3(126 * 24), t256, 0, stream>>>(
        h2h, WtF1, fc1_b, nullptr, nullptr, nullptr, bufA, 24, 3072, 768, 16128);
    // FC2: M=16128 (126 mt), N=768 (gn=6), K=3072; guard gr<16000
    gemm128<EFC2><<<dim3(126 * 6), t256, 0, stream>>>(
        bufA, WtF2, fc2_b, ls2, nullptr, outh, nullptr, 6, 768, 3072, 16000);
  }
}

// Round 6
// 677.523 us; speedup vs baseline: 1.5621x; 1.2862x over previous
//
#include <hip/hip_runtime.h>
#include <hip/hip_bf16.h>

typedef unsigned short u16;
typedef unsigned char u8;
typedef __attribute__((ext_vector_type(8))) short bh8;   // 8 x bf16
typedef __attribute__((ext_vector_type(4))) float fx4;   // MFMA accumulator
typedef __attribute__((ext_vector_type(4))) int i32x4;
typedef __attribute__((ext_vector_type(8))) int i32x8;   // 32 fp8 bytes

__device__ __forceinline__ u16 f2bf(float f) {
  union { float f; unsigned u; } v; v.f = f;
  unsigned r = v.u + 0x7FFFu + ((v.u >> 16) & 1u);  // RNE
  return (u16)(r >> 16);
}

// f32 -> OCP e4m3fn, RNE, clamp to +-448
__device__ __forceinline__ u8 f2fp8(float x) {
  union { float f; unsigned u; } v; v.f = x;
  const unsigned sign = (v.u >> 24) & 0x80u;
  v.u &= 0x7FFFFFFFu;
  if (v.f >= 464.0f) return (u8)(sign | 0x7Eu);
  if (v.f < 0.015625f) {                       // subnormal: step 2^-9
    int q = (int)rintf(v.f * 512.0f);          // 0..8 (8 == first normal)
    return (u8)(sign | (unsigned)q);
  }
  unsigned u2 = v.u + 0x7FFFFu + ((v.u >> 20) & 1u);
  unsigned e2 = (u2 >> 23) - 127u + 7u;
  unsigned mant = (u2 >> 20) & 7u;
  return (u8)(sign | (e2 << 3) | mant);
}

__device__ __forceinline__ void gload_lds16(const void* g, void* l) {
  __builtin_amdgcn_global_load_lds(
      (const __attribute__((address_space(1))) void*)g,
      (__attribute__((address_space(3))) void*)l, 16, 0, 0);
}

__device__ __forceinline__ i32x8 rd32(const char* p0, const char* p1) {
  i32x4 lo = *(const i32x4*)p0;
  i32x4 hi = *(const i32x4*)p1;
  return __builtin_shufflevector(lo, hi, 0, 1, 2, 3, 4, 5, 6, 7);
}

// ---------------- weight transpose + f32->fp8(x32) : W[K][N] -> Wt[N][K] ----------------
__global__ __launch_bounds__(256) void transp_cvt(
    const float* __restrict__ W, u8* __restrict__ Wt, int K, int N) {
  __shared__ float tile[32][33];
  const int k0 = blockIdx.x * 32, n0 = blockIdx.y * 32;
  const int tx = threadIdx.x & 31, ty = threadIdx.x >> 5;  // ty 0..7
#pragma unroll
  for (int i = 0; i < 4; ++i)
    tile[ty + i * 8][tx] = W[(size_t)(k0 + ty + i * 8) * N + n0 + tx];
  __syncthreads();
#pragma unroll
  for (int i = 0; i < 4; ++i)
    Wt[(size_t)(n0 + ty + i * 8) * K + k0 + tx] = f2fp8(tile[tx][ty + i * 8] * 32.0f);
}

// ---------------- block reduce ----------------
__device__ __forceinline__ float blockSum(float v, float* sh) {
#pragma unroll
  for (int m = 32; m; m >>= 1) v += __shfl_xor(v, m);
  if ((threadIdx.x & 63) == 0) sh[threadIdx.x >> 6] = v;
  __syncthreads();
  return sh[0] + sh[1] + sh[2] + sh[3];
}

// ---------------- LN1: x[b, j] -> hw windowed/rolled fp8(x4) [16][2048][768] ----------------
__global__ __launch_bounds__(256) void ln1_k(
    const float* __restrict__ x, const float* __restrict__ w,
    const float* __restrict__ b, u8* __restrict__ hw) {
  __shared__ float sh1[4], sh2[4];
  const int row = blockIdx.x;            // 0..32767 (b*2048 + i, rolled coords)
  const int bI = row >> 11, i = row & 2047;
  const int j = (i + 64) & 2047;         // source (unrolled) index
  const int tid = threadIdx.x;
  u8* dst = hw + (size_t)row * 768;
  if (j >= 2000) {                       // padded region -> zeros
    dst[tid] = 0; dst[tid + 256] = 0; dst[tid + 512] = 0;
    return;
  }
  const float* xr = x + ((size_t)bI * 2000 + j) * 768;
  float v0 = xr[tid], v1 = xr[tid + 256], v2 = xr[tid + 512];
  float mean = blockSum(v0 + v1 + v2, sh1) * (1.0f / 768.0f);
  float d0 = v0 - mean, d1 = v1 - mean, d2 = v2 - mean;
  float var = blockSum(d0 * d0 + d1 * d1 + d2 * d2, sh2) * (1.0f / 768.0f);
  float rs = rsqrtf(var + 1e-5f);
  dst[tid]       = f2fp8((d0 * rs * w[tid]       + b[tid])       * 4.0f);
  dst[tid + 256] = f2fp8((d1 * rs * w[tid + 256] + b[tid + 256]) * 4.0f);
  dst[tid + 512] = f2fp8((d2 * rs * w[tid + 512] + b[tid + 512]) * 4.0f);
}

// ---------------- LN2: x2 (f32) -> h2 fp8(x4) ----------------
__global__ __launch_bounds__(256) void ln2_k(
    const float* __restrict__ src, const float* __restrict__ w,
    const float* __restrict__ b, u8* __restrict__ dsth) {
  __shared__ float sh1[4], sh2[4];
  const int row = blockIdx.x;
  const int tid = threadIdx.x;
  const float* xr = src + (size_t)row * 768;
  u8* dst = dsth + (size_t)row * 768;
  float v0 = xr[tid], v1 = xr[tid + 256], v2 = xr[tid + 512];
  float mean = blockSum(v0 + v1 + v2, sh1) * (1.0f / 768.0f);
  float d0 = v0 - mean, d1 = v1 - mean, d2 = v2 - mean;
  float var = blockSum(d0 * d0 + d1 * d1 + d2 * d2, sh2) * (1.0f / 768.0f);
  float rs = rsqrtf(var + 1e-5f);
  dst[tid]       = f2fp8((d0 * rs * w[tid]       + b[tid])       * 4.0f);
  dst[tid + 256] = f2fp8((d1 * rs * w[tid + 256] + b[tid + 256]) * 4.0f);
  dst[tid + 512] = f2fp8((d2 * rs * w[tid + 512] + b[tid + 512]) * 4.0f);
}

// ================= 128x128 fp8 GEMM, BK=128, MX-scaled MFMA K=128 =================
// C = A[M,K] * Bt[N,K]^T (true values). A stored x4 (scaleA=125 -> 2^-2),
// Bt stored x32 (scaleB=122 -> 2^-5). 256 thr (2x2 waves, 64x64 each).
// LDS: As[128][128] + Bs[128][128] fp8 = 32 KiB. XOR swizzle byte^((row&7)<<4).
enum { EQKV = 0, EPROJ = 1, EFC1 = 2, EFC2 = 3 };

template <int EPI>
__global__ __launch_bounds__(256, 3) void gemm128f8(
    const u8* __restrict__ A, const u8* __restrict__ Bt,
    const float* __restrict__ bias, const float* __restrict__ lsv,
    const float* __restrict__ resid, float* __restrict__ outf,
    u16* __restrict__ outh, u8* __restrict__ outb,
    int gn, int N, int K, int mValid) {
  __shared__ u8 As[16384];  // [128][128]
  __shared__ u8 Bs[16384];
  const int tid = threadIdx.x;
  const int lane = tid & 63, wid = tid >> 6;
  const int wr = wid >> 1, wc = wid & 1;

  // bijective XCD swizzle (m204); nt-fast order -> A-panel stays in XCD L2
  const int nwg = gridDim.x, bid = blockIdx.x;
  const int q = nwg >> 3, r = nwg & 7;
  const int xcd = bid & 7, idx = bid >> 3;
  const int wg = (xcd < r ? xcd * (q + 1) : r * (q + 1) + (xcd - r) * q) + idx;
  const int mt = wg / gn, nt = wg % gn;
  const int m0 = mt * 128, n0 = nt * 128;
  const int NT = K >> 7;

  fx4 acc[4][4];
#pragma unroll
  for (int i = 0; i < 4; ++i)
#pragma unroll
    for (int j = 0; j < 4; ++j) acc[i][j] = fx4{0.f, 0.f, 0.f, 0.f};

  // read-side: lane holds row = base+rsel, k-bytes [kgrp*32, +32)
  const int rsel = lane & 15, kgrp = lane >> 4;
  const int colb = kgrp * 32;
  const int xorc = (rsel & 7) << 4;

  // stage-side: thread stages rows rl+32i, 16B chunk (tid&7)^(row&7)
  const int rl = tid >> 3;                         // 0..31
  const int kc16 = ((tid & 7) ^ (rl & 7)) * 16;    // pre-swizzled source col
  const u8* aRow = A + (size_t)(m0 + rl) * K + kc16;
  const u8* bRow = Bt + (size_t)(n0 + rl) * K + kc16;
  char* aDst = (char*)As + wid * 1024;
  char* bDst = (char*)Bs + wid * 1024;

  for (int t = 0; t < NT; ++t) {
    const int k0 = t << 7;
#pragma unroll
    for (int i = 0; i < 4; ++i) {
      gload_lds16(aRow + (size_t)k0 + (size_t)(i * 32) * K, aDst + i * 4096);
      gload_lds16(bRow + (size_t)k0 + (size_t)(i * 32) * K, bDst + i * 4096);
    }
    __syncthreads();
    i32x8 af[4];
#pragma unroll
    for (int mi = 0; mi < 4; ++mi) {
      const char* ab = (const char*)As + (wr * 64 + mi * 16 + rsel) * 128;
      af[mi] = rd32(ab + (colb ^ xorc), ab + ((colb + 16) ^ xorc));
    }
#pragma unroll
    for (int ni = 0; ni < 4; ++ni) {
      const char* bb = (const char*)Bs + (wc * 64 + ni * 16 + rsel) * 128;
      i32x8 bfr = rd32(bb + (colb ^ xorc), bb + ((colb + 16) ^ xorc));
#pragma unroll
      for (int mi = 0; mi < 4; ++mi)
        acc[mi][ni] = __builtin_amdgcn_mfma_scale_f32_16x16x128_f8f6f4(
            af[mi], bfr, acc[mi][ni], 0, 0, 0, 125, 0, 122);
    }
    __syncthreads();
  }

  // epilogue; C/D layout: col = lane&15, row = (lane>>4)*4 + j   [m89-verified]
  const int cc = lane & 15;
  const int rq = (lane >> 4) * 4;
#pragma unroll
  for (int ni = 0; ni < 4; ++ni) {
    const int gc = n0 + wc * 64 + ni * 16 + cc;
    const float bv = bias[gc];
    const float ls = (EPI == EPROJ || EPI == EFC2) ? lsv[gc] : 0.f;
#pragma unroll
    for (int mi = 0; mi < 4; ++mi) {
#pragma unroll
      for (int j = 0; j < 4; ++j) {
        const int gr = m0 + wr * 64 + mi * 16 + rq + j;
        const float v = acc[mi][ni][j] + bv;
        if (EPI == EQKV) {
          outh[(size_t)gr * N + gc] = f2bf(v);
        } else if (EPI == EFC1) {
          const float t2 = 0.5f * v * (1.0f + erff(v * 0.70710678118654752f));
          outb[(size_t)gr * N + gc] = f2fp8(t2 * 4.0f);
        } else if (EPI == EFC2) {
          if (gr < mValid) {
            const size_t o = (size_t)gr * 768 + gc;
            outf[o] += v * ls;
          }
        } else {  // EPROJ: unroll(+64), crop, x2 = x + a*ls1
          const int bI = gr >> 11, ip = gr & 2047;
          const int jj = (ip + 64) & 2047;
          if (jj < 2000) {
            const size_t o = ((size_t)bI * 2000 + jj) * 768 + gc;
            outf[o] = resid[o] + v * ls;
          }
        }
      }
    }
  }
}

// ---------------- window attention: one block per (window, head) ----------------
struct AttnLds {
  union {
    struct { u16 Qs[128][72]; u16 Ks[128][72]; } qk;  // 36864 B
    u16 Ps[128][136];                                  // 34816 B
  } u;
  u16 Vt[64][136];   // V^T: [d][kk], 17408 B
  float biasv[256];  // rel_bias column for this head
};

__global__ __launch_bounds__(256, 2) void attn_k(
    const u16* __restrict__ qkv, const float* __restrict__ rel_bias,
    u8* __restrict__ aout) {
  __shared__ AttnLds L;
  const int blk = blockIdx.x;
  const int w = blk / 12, h = blk - w * 12;
  const int wi = w & 15;  // window index within batch
  const int tid = threadIdx.x;
  const int lane = tid & 63, wid = tid >> 6;

  if (tid < 255) L.biasv[tid] = rel_bias[tid * 12 + h];

  const size_t rowbase = (size_t)w * 128;
#pragma unroll
  for (int i = 0; i < 4; ++i) {
    const int idx = tid + i * 256;          // 0..1023
    const int r = idx >> 3, seg = idx & 7;  // 128 rows x 8 segs of 8
    const u16* src = qkv + (rowbase + r) * 2304 + h * 64 + seg * 8;
    *(bh8*)&L.u.qk.Qs[r][seg * 8] = *(const bh8*)(src);
    *(bh8*)&L.u.qk.Ks[r][seg * 8] = *(const bh8*)(src + 768);
    bh8 vv = *(const bh8*)(src + 1536);
#pragma unroll
    for (int e = 0; e < 8; ++e) L.Vt[seg * 8 + e][r] = ((const u16*)&vv)[e];
  }
  __syncthreads();

  // QK^T: each wave owns 32 q-rows x all 128 k-cols
  const int R0 = wid * 32;
  const int rsel = lane & 15, kgrp = lane >> 4;
  fx4 s[2][8];
#pragma unroll
  for (int mi = 0; mi < 2; ++mi)
#pragma unroll
    for (int ni = 0; ni < 8; ++ni) s[mi][ni] = fx4{0.f, 0.f, 0.f, 0.f};

#pragma unroll
  for (int ks = 0; ks < 2; ++ks) {
    bh8 aq[2], bk[8];
#pragma unroll
    for (int mi = 0; mi < 2; ++mi)
      aq[mi] = *(const bh8*)&L.u.qk.Qs[R0 + mi * 16 + rsel][ks * 32 + kgrp * 8];
#pragma unroll
    for (int ni = 0; ni < 8; ++ni)
      bk[ni] = *(const bh8*)&L.u.qk.Ks[ni * 16 + rsel][ks * 32 + kgrp * 8];
#pragma unroll
    for (int mi = 0; mi < 2; ++mi)
#pragma unroll
      for (int ni = 0; ni < 8; ++ni)
        s[mi][ni] = __builtin_amdgcn_mfma_f32_16x16x32_bf16(aq[mi], bk[ni], s[mi][ni], 0, 0, 0);
  }

  // scale + rel-bias + mask + row softmax (rows live in a 16-lane group)
#pragma unroll
  for (int mi = 0; mi < 2; ++mi) {
#pragma unroll
    for (int j = 0; j < 4; ++j) {
      const int r = R0 + mi * 16 + kgrp * 4 + j;
      float vals[8];
      float mx = -1e30f;
#pragma unroll
      for (int ni = 0; ni < 8; ++ni) {
        const int c = ni * 16 + rsel;
        const int ic = wi * 128 + c;
        const bool valid = ((ic + 64) & 2047) < 2000;
        const float v = valid ? (s[mi][ni][j] * 0.125f + L.biasv[c - r + 127]) : -1e30f;
        vals[ni] = v;
        mx = fmaxf(mx, v);
      }
#pragma unroll
      for (int mm = 8; mm; mm >>= 1) mx = fmaxf(mx, __shfl_xor(mx, mm));
      float sum = 0.f;
#pragma unroll
      for (int ni = 0; ni < 8; ++ni) { float p = __expf(vals[ni] - mx); vals[ni] = p; sum += p; }
#pragma unroll
      for (int mm = 8; mm; mm >>= 1) sum += __shfl_xor(sum, mm);
      const float inv = 1.0f / sum;
#pragma unroll
      for (int ni = 0; ni < 8; ++ni) s[mi][ni][j] = vals[ni] * inv;
    }
  }
  __syncthreads();  // all QK^T LDS reads done before P overwrites Q/K (union)

#pragma unroll
  for (int mi = 0; mi < 2; ++mi)
#pragma unroll
    for (int ni = 0; ni < 8; ++ni)
#pragma unroll
      for (int j = 0; j < 4; ++j)
        L.u.Ps[R0 + mi * 16 + kgrp * 4 + j][ni * 16 + rsel] = f2bf(s[mi][ni][j]);
  __syncthreads();

  // PV: out 32x64 per wave
  fx4 o[2][4];
#pragma unroll
  for (int mi = 0; mi < 2; ++mi)
#pragma unroll
    for (int ni = 0; ni < 4; ++ni) o[mi][ni] = fx4{0.f, 0.f, 0.f, 0.f};
#pragma unroll
  for (int ks = 0; ks < 4; ++ks) {
    bh8 ap[2], bv[4];
#pragma unroll
    for (int mi = 0; mi < 2; ++mi)
      ap[mi] = *(const bh8*)&L.u.Ps[R0 + mi * 16 + rsel][ks * 32 + kgrp * 8];
#pragma unroll
    for (int ni = 0; ni < 4; ++ni)
      bv[ni] = *(const bh8*)&L.Vt[ni * 16 + rsel][ks * 32 + kgrp * 8];
#pragma unroll
    for (int mi = 0; mi < 2; ++mi)
#pragma unroll
      for (int ni = 0; ni < 4; ++ni)
        o[mi][ni] = __builtin_amdgcn_mfma_f32_16x16x32_bf16(ap[mi], bv[ni], o[mi][ni], 0, 0, 0);
  }

#pragma unroll
  for (int mi = 0; mi < 2; ++mi)
#pragma unroll
    for (int ni = 0; ni < 4; ++ni)
#pragma unroll
      for (int j = 0; j < 4; ++j)
        aout[(rowbase + R0 + mi * 16 + kgrp * 4 + j) * 768 + h * 64 + ni * 16 + rsel] =
            f2fp8(o[mi][ni][j] * 4.0f);
}

// ---------------- host ----------------
extern "C" void kernel_launch(void* const* d_in, const int* in_sizes, int n_in,
                              void* d_out, int out_size, void* d_ws, size_t ws_size,
                              hipStream_t stream) {
  (void)in_sizes; (void)n_in; (void)out_size; (void)ws_size;
  const float* x        = (const float*)d_in[0];
  const float* n1w      = (const float*)d_in[1];
  const float* n1b      = (const float*)d_in[2];
  const float* qkv_w    = (const float*)d_in[3];
  const float* qkv_b    = (const float*)d_in[4];
  const float* proj_w   = (const float*)d_in[5];
  const float* proj_b   = (const float*)d_in[6];
  const float* rel_bias = (const float*)d_in[7];
  const float* ls1      = (const float*)d_in[8];
  const float* n2w      = (const float*)d_in[9];
  const float* n2b      = (const float*)d_in[10];
  const float* fc1_w    = (const float*)d_in[11];
  const float* fc1_b    = (const float*)d_in[12];
  const float* fc2_w    = (const float*)d_in[13];
  const float* fc2_b    = (const float*)d_in[14];
  const float* ls2      = (const float*)d_in[15];
  float* out = (float*)d_out;

  char* ws = (char*)d_ws;
  u8*  WtQ   = (u8*)(ws);                           // 2304x768 fp8
  u8*  WtP   = (u8*)(ws + 3538944);                 // 768x768 fp8
  u8*  WtF1  = (u8*)(ws + 4718592);                 // 3072x768 fp8
  u8*  WtF2  = (u8*)(ws + 9437184);                 // 768x3072 fp8
  u8*  bufB8 = (u8*)(ws + 14155776);                // LN1/attn/h2 fp8 (<=26 MB)
  char* bufA = ws + 14155776 + 50331648;            // QKV bf16 151MB / FC1 fp8 49.5MB
  u16* bufA16 = (u16*)bufA;
  u8*  bufA8  = (u8*)bufA;

  dim3 t256(256);
  transp_cvt<<<dim3(24, 72), t256, 0, stream>>>(qkv_w, WtQ, 768, 2304);
  transp_cvt<<<dim3(24, 24), t256, 0, stream>>>(proj_w, WtP, 768, 768);
  transp_cvt<<<dim3(24, 96), t256, 0, stream>>>(fc1_w, WtF1, 768, 3072);
  transp_cvt<<<dim3(96, 24), t256, 0, stream>>>(fc2_w, WtF2, 3072, 768);

  ln1_k<<<32768, t256, 0, stream>>>(x, n1w, n1b, bufB8);
  // QKV: M=32768, N=2304 (gn=18), K=768 -> bf16 out for attn
  gemm128f8<EQKV><<<dim3(256 * 18), t256, 0, stream>>>(
      bufB8, WtQ, qkv_b, nullptr, nullptr, nullptr, bufA16, nullptr, 18, 2304, 768, 32768);
  attn_k<<<3072, t256, 0, stream>>>(bufA16, rel_bias, bufB8);
  // PROJ: M=32768, N=768 (gn=6), K=768
  gemm128f8<EPROJ><<<dim3(256 * 6), t256, 0, stream>>>(
      bufB8, WtP, proj_b, ls1, x, out, nullptr, nullptr, 6, 768, 768, 32768);
  ln2_k<<<32000, t256, 0, stream>>>(out, n2w, n2b, bufB8);
  for (int half = 0; half < 2; ++half) {
    const u8* h2h = bufB8 + (size_t)half * 16000 * 768;
    float* outh = out + (size_t)half * 16000 * 768;
    // FC1: M=16128 (126 mt), N=3072 (gn=24), K=768 -> fp8(x4) out
    gemm128f8<EFC1><<<dim3(126 * 24), t256, 0, stream>>>(
        h2h, WtF1, fc1_b, nullptr, nullptr, nullptr, nullptr, bufA8, 24, 3072, 768, 16128);
    // FC2: M=16128 (126 mt), N=768 (gn=6), K=3072; guard gr<16000
    gemm128f8<EFC2><<<dim3(126 * 6), t256, 0, stream>>>(
        bufA8, WtF2, fc2_b, ls2, nullptr, outh, nullptr, nullptr, 6, 768, 3072, 16000);
  }
}